// Round 3
// baseline (39.471 us; speedup 1.0000x reference)
//
#include <hip/hip_runtime.h>
#include <math.h>

#define N 4096
#define HALF 2048       // j-range per pass block
#define RPB 32          // rows per pass block
#define LANES 16        // j-lanes per row
#define NRB (N / RPB)   // 128 row-blocks
#define NPASS (NRB * 2) // 256 pass blocks (row-block x j-half)
#define FEPS 1e-7f

// ---------------------------------------------------------------------------
// ws layout (bytes):
//   [0,8)      double wd_focal
//   [16,20)    int    counter
//   [64 ..)    float rowA_p[2*N], rowB_p[2*N]   (pass-1 partial row sums)
//              float pABr[2*N], pAAr[2*N], pBBr[2*N] (pass-2 partial row sums)
// ---------------------------------------------------------------------------

__device__ __forceinline__ double block_reduce(double v) {
    __shared__ double buf[4];
    int tid = threadIdx.x;
    #pragma unroll
    for (int o = 32; o > 0; o >>= 1) v += __shfl_down(v, o, 64);
    __syncthreads();
    if ((tid & 63) == 0) buf[tid >> 6] = v;
    __syncthreads();
    return buf[0] + buf[1] + buf[2] + buf[3];
}

// ---------------------------------------------------------------------------
// K1: blocks 0..255 -> pass-1 partial row sums over their j-half (no atomics);
//     block 256 -> focal BCE + counter reset
// ---------------------------------------------------------------------------
__global__ __launch_bounds__(256) void k1(
        const float* __restrict__ target,
        const float* __restrict__ output,
        const float* __restrict__ y_class,
        const float* __restrict__ y_pred_class,
        const float* __restrict__ v1,
        const float* __restrict__ v2,
        const float* __restrict__ w,
        double* __restrict__ wd,
        int* __restrict__ counter,
        float* __restrict__ rowA_p,
        float* __restrict__ rowB_p) {
    int tid = threadIdx.x;
    int b = blockIdx.x;

    if (b == NPASS) {
        // ------------------ focal BCE block ------------------
        if (tid == 0) *counter = 0;
        double s_ypc = 0.0, s_ypc2 = 0.0, s_yc = 0.0;
        for (int i = tid; i < N; i += 256) {
            float ypc = y_pred_class[i];
            s_ypc  += (double)ypc;
            s_ypc2 += (double)ypc * (double)ypc;
            s_yc   += (double)y_class[i];
        }
        double t_ypc  = block_reduce(s_ypc);
        double t_ypc2 = block_reduce(s_ypc2);
        double t_yc   = block_reduce(s_yc);

        __shared__ float  sm, sinv2s;
        __shared__ double s_sum1myc;
        if (tid == 0) {
            double m   = t_ypc / (double)N;
            double var = t_ypc2 / (double)N - m * m;
            double sd  = sqrt(var > 0.0 ? var : 0.0);
            sm     = (float)m;
            sinv2s = (float)(1.0 / (2.0 * sd));
            s_sum1myc = (double)N - t_yc;
        }
        __syncthreads();

        float m = sm, inv2s = sinv2s;
        double s_cwf = 0.0, s_cwfb = 0.0;
        for (int i = tid; i < N; i += 256) {
            float yc  = y_class[i];
            float ypc = y_pred_class[i];
            float nrm = (ypc - m) * inv2s + 0.5f;
            nrm = fminf(fmaxf(nrm, 0.0f), 1.0f);
            float c1  = (1.0f - yc) * nrm;
            float cwf = c1 * c1;                    // GAMMA = 2
            float x = fminf(fmaxf(output[i], FEPS), 1.0f - FEPS);
            float t = target[i];
            float bce = -t * logf(x) - (1.0f - t) * logf(1.0f - x);
            s_cwf  += (double)cwf;
            s_cwfb += (double)cwf * (double)bce;
        }
        double t_cwf  = block_reduce(s_cwf);
        double t_cwfb = block_reduce(s_cwfb);
        if (tid == 0) wd[0] = t_cwfb * (s_sum1myc / t_cwf) / (double)N;
        return;
    }

    // ------------------ pass-1 blocks: 32 rows x 2048-j half ------------------
    int h  = b & 1;
    int rb = b >> 1;
    int j0 = h * HALF;
    __shared__ float s1[HALF], s2[HALF], sw[HALF];   // 24 KiB
    for (int t = tid * 4; t < HALF; t += 1024) {
        *(float4*)&s1[t] = *(const float4*)&v1[j0 + t];
        *(float4*)&s2[t] = *(const float4*)&v2[j0 + t];
        *(float4*)&sw[t] = *(const float4*)&w [j0 + t];
    }
    __syncthreads();

    int lane = tid & (LANES - 1);
    int g    = tid >> 4;
    int i0   = rb * RPB + g * 2;     // 2 rows per thread
    float a0 = v1[i0],     a1 = v1[i0 + 1];
    float b0 = v2[i0],     b1 = v2[i0 + 1];
    float sa0 = 0.f, sa1 = 0.f, sb0 = 0.f, sb1 = 0.f;
    #pragma unroll 8
    for (int k = 0; k < HALF / (LANES * 4); ++k) {   // 32 float4 steps
        int j = 4 * lane + 64 * k;
        float4 x1 = *(const float4*)&s1[j];
        float4 x2 = *(const float4*)&s2[j];
        float4 xw = *(const float4*)&sw[j];
        #define P1(c)                                  \
        {                                              \
            sa0 = fmaf(fabsf(a0 - x1.c), xw.c, sa0);   \
            sa1 = fmaf(fabsf(a1 - x1.c), xw.c, sa1);   \
            sb0 = fmaf(fabsf(b0 - x2.c), xw.c, sb0);   \
            sb1 = fmaf(fabsf(b1 - x2.c), xw.c, sb1);   \
        }
        P1(x) P1(y) P1(z) P1(w)
        #undef P1
    }
    #pragma unroll
    for (int o = 1; o < LANES; o <<= 1) {
        sa0 += __shfl_xor(sa0, o, LANES);
        sa1 += __shfl_xor(sa1, o, LANES);
        sb0 += __shfl_xor(sb0, o, LANES);
        sb1 += __shfl_xor(sb1, o, LANES);
    }
    if (lane == 0) {
        rowA_p[h * N + i0]     = sa0;
        rowA_p[h * N + i0 + 1] = sa1;
        rowB_p[h * N + i0]     = sb0;
        rowB_p[h * N + i0 + 1] = sb1;
    }
}

// ---------------------------------------------------------------------------
// K2: pass-2 centered products (32 rows x 2048-j half per block, 2 rows/thread)
//     + last-block final reduction
// ---------------------------------------------------------------------------
__global__ __launch_bounds__(256) void k2(
        const float* __restrict__ v1,
        const float* __restrict__ v2,
        const float* __restrict__ w,
        const float* __restrict__ rowA_p,
        const float* __restrict__ rowB_p,
        const double* __restrict__ wd,
        const int* __restrict__ power,
        int* __restrict__ counter,
        float* __restrict__ pABr,
        float* __restrict__ pAAr,
        float* __restrict__ pBBr,
        float* __restrict__ out) {
    __shared__ float s1[HALF], s2[HALF], sw[HALF], sav[HALF], sbv[HALF]; // 40 KiB
    int tid = threadIdx.x;
    int b = blockIdx.x;
    int h  = b & 1;
    int rb = b >> 1;
    int j0 = h * HALF;
    const float invN = 1.0f / (float)N;

    // stage this block's j-half; combine pass-1 halves into full row means
    for (int t = tid * 4; t < HALF; t += 1024) {
        *(float4*)&s1[t] = *(const float4*)&v1[j0 + t];
        *(float4*)&s2[t] = *(const float4*)&v2[j0 + t];
        *(float4*)&sw[t] = *(const float4*)&w [j0 + t];
        float4 r0 = *(const float4*)&rowA_p[j0 + t];
        float4 r1 = *(const float4*)&rowA_p[N + j0 + t];
        float4 q0 = *(const float4*)&rowB_p[j0 + t];
        float4 q1 = *(const float4*)&rowB_p[N + j0 + t];
        float4 ra, rbv;
        ra.x  = (r0.x + r1.x) * invN;  ra.y  = (r0.y + r1.y) * invN;
        ra.z  = (r0.z + r1.z) * invN;  ra.w  = (r0.w + r1.w) * invN;
        rbv.x = (q0.x + q1.x) * invN;  rbv.y = (q0.y + q1.y) * invN;
        rbv.z = (q0.z + q1.z) * invN;  rbv.w = (q0.w + q1.w) * invN;
        *(float4*)&sav[t] = ra;
        *(float4*)&sbv[t] = rbv;
    }
    __syncthreads();

    // grand means gA,gB (redundant per block; partials are L2-hit)
    double sgA = 0.0, sgB = 0.0;
    for (int i = tid; i < N; i += 256) {
        double wi = (double)w[i];
        sgA += (double)(rowA_p[i] + rowA_p[N + i]) * wi;
        sgB += (double)(rowB_p[i] + rowB_p[N + i]) * wi;
    }
    const double NN = (double)N * (double)N;
    float gA = (float)(block_reduce(sgA) / NN);
    float gB = (float)(block_reduce(sgB) / NN);

    int lane = tid & (LANES - 1);
    int g    = tid >> 4;
    int i0   = rb * RPB + g * 2;
    float a0 = v1[i0],   a1 = v1[i0 + 1];
    float e0 = v2[i0],   e1 = v2[i0 + 1];
    float cA0 = (rowA_p[i0]     + rowA_p[N + i0])     * invN - gA;
    float cA1 = (rowA_p[i0 + 1] + rowA_p[N + i0 + 1]) * invN - gA;
    float cB0 = (rowB_p[i0]     + rowB_p[N + i0])     * invN - gB;
    float cB1 = (rowB_p[i0 + 1] + rowB_p[N + i0 + 1]) * invN - gB;

    float ab0 = 0.f, aa0 = 0.f, bb0 = 0.f;
    float ab1 = 0.f, aa1 = 0.f, bb1 = 0.f;
    #pragma unroll 4
    for (int k = 0; k < HALF / (LANES * 4); ++k) {   // 32 float4 steps
        int j = 4 * lane + 64 * k;
        float4 x1 = *(const float4*)&s1[j];
        float4 x2 = *(const float4*)&s2[j];
        float4 xw = *(const float4*)&sw[j];
        float4 xa = *(const float4*)&sav[j];
        float4 xb = *(const float4*)&sbv[j];
        #define P2(c)                                            \
        {                                                        \
            float Am0 = fabsf(a0 - x1.c) - xa.c - cA0;           \
            float Bm0 = fabsf(e0 - x2.c) - xb.c - cB0;           \
            float Am1 = fabsf(a1 - x1.c) - xa.c - cA1;           \
            float Bm1 = fabsf(e1 - x2.c) - xb.c - cB1;           \
            float Aw0 = Am0 * xw.c, Bw0 = Bm0 * xw.c;            \
            float Aw1 = Am1 * xw.c, Bw1 = Bm1 * xw.c;            \
            ab0 = fmaf(Aw0, Bm0, ab0);                           \
            aa0 = fmaf(Aw0, Am0, aa0);                           \
            bb0 = fmaf(Bw0, Bm0, bb0);                           \
            ab1 = fmaf(Aw1, Bm1, ab1);                           \
            aa1 = fmaf(Aw1, Am1, aa1);                           \
            bb1 = fmaf(Bw1, Bm1, bb1);                           \
        }
        P2(x) P2(y) P2(z) P2(w)
        #undef P2
    }
    #pragma unroll
    for (int o = 1; o < LANES; o <<= 1) {
        ab0 += __shfl_xor(ab0, o, LANES);
        aa0 += __shfl_xor(aa0, o, LANES);
        bb0 += __shfl_xor(bb0, o, LANES);
        ab1 += __shfl_xor(ab1, o, LANES);
        aa1 += __shfl_xor(aa1, o, LANES);
        bb1 += __shfl_xor(bb1, o, LANES);
    }
    if (lane == 0) {
        pABr[h * N + i0]     = ab0;
        pABr[h * N + i0 + 1] = ab1;
        pAAr[h * N + i0]     = aa0;
        pAAr[h * N + i0 + 1] = aa1;
        pBBr[h * N + i0]     = bb0;
        pBBr[h * N + i0 + 1] = bb1;
    }

    // ---- last-block-done final reduction ----
    __shared__ int isLast;
    if (tid == 0) {
        __threadfence();
        int old = atomicAdd(counter, 1);
        isLast = (old == NPASS - 1);
    }
    __syncthreads();
    if (!isLast) return;
    __threadfence();

    double sab = 0.0, saa = 0.0, sbb = 0.0;
    for (int i = tid; i < N; i += 256) {
        double wi = (double)w[i];
        sab += fabs((double)(pABr[i] + pABr[N + i])) * wi;
        saa += (double)(pAAr[i] + pAAr[N + i]) * wi;
        sbb += (double)(pBBr[i] + pBBr[N + i]) * wi;
    }
    double tab = block_reduce(sab);
    double taa = block_reduce(saa);
    double tbb = block_reduce(sbb);
    if (tid == 0) {
        double mAB = tab / NN;
        double mAA = taa / NN;
        double mBB = tbb / NN;
        int p = power[0];
        double d;
        if (p == 1) {
            d = mAB / sqrt(fabs(mAA * mBB) + 1e-12);
        } else if (p == 2) {
            d = (mAB * mAB) / (fabs(mAA * mBB) + 1e-12);
        } else {
            d = pow(mAB / sqrt(mAA * mBB) + 1e-12, (double)p);
        }
        if (isnan(d)) d = 0.0;
        if (d < 0.0)  d = 0.0;
        out[0] = (float)(wd[0] + 1000.0 * d);
    }
}

// ---------------------------------------------------------------------------
extern "C" void kernel_launch(void* const* d_in, const int* in_sizes, int n_in,
                              void* d_out, int out_size, void* d_ws, size_t ws_size,
                              hipStream_t stream) {
    const float* target       = (const float*)d_in[0];
    const float* output       = (const float*)d_in[1];
    const float* y_class      = (const float*)d_in[2];
    const float* y_pred_class = (const float*)d_in[3];
    const float* var_1        = (const float*)d_in[4];
    const float* var_2        = (const float*)d_in[5];
    const float* normedweight = (const float*)d_in[6];
    const int*   power        = (const int*)d_in[7];
    float* out = (float*)d_out;

    char*   ws      = (char*)d_ws;
    double* wd      = (double*)ws;
    int*    counter = (int*)(ws + 16);
    float*  rowA_p  = (float*)(ws + 64);
    float*  rowB_p  = rowA_p + 2 * N;
    float*  pABr    = rowB_p + 2 * N;
    float*  pAAr    = pABr  + 2 * N;
    float*  pBBr    = pAAr  + 2 * N;

    k1<<<NPASS + 1, 256, 0, stream>>>(target, output, y_class, y_pred_class,
                                      var_1, var_2, normedweight, wd, counter,
                                      rowA_p, rowB_p);
    k2<<<NPASS, 256, 0, stream>>>(var_1, var_2, normedweight, rowA_p, rowB_p,
                                  wd, power, counter, pABr, pAAr, pBBr, out);
}